// Round 2
// baseline (774.862 us; speedup 1.0000x reference)
//
#include <hip/hip_runtime.h>

#define N_    4096
#define D_    256
#define N2    8192
#define BM    32
#define BN    128
#define KC    64
#define CPAD  4

constexpr float INV_TEMP = 10.0f;   // 1/0.1
constexpr float NEGINF   = -1e30f;

__device__ __forceinline__ const float* frow(const float* f, int r) {
    // row r of the [2N, D] matrix stored as features[N][2][D]
    return f + (size_t)(r & (N_ - 1)) * (2 * D_) + (size_t)((r >> 12) * D_);
}

// ---------------- Phase A: fused f@f^T with online per-row NEGATIVE-set LSE ----------------
// stats layout: [0]=c_id  = log(sum_{id-negs} exp(lg)),  per row (8192 floats)
//               [1]=c_cam = log(sum_{cam-negs} exp(lg)), per row (8192 floats)
// id-neg: label mismatch. cam-neg: !(label match && cam match). Diagonal excluded
// from both automatically (same label & cam as itself).
__global__ __launch_bounds__(512) void phaseA(const float* __restrict__ feat,
                                              const int* __restrict__ label,
                                              const int* __restrict__ camid,
                                              float* __restrict__ stats) {
    __shared__ __align__(16) float rowS[BM][D_];          // 32 KB, persistent
    __shared__ __align__(16) float colS[KC][BN + CPAD];   // 33.8 KB, k-major, padded

    const int tid = threadIdx.x;
    const int tx = tid & 31;       // 32 col-groups
    const int ty = tid >> 5;       // 16 row-groups (2 rows each)
    const int rowBase = blockIdx.x * BM;

    // ---- load this block's 32 rows into LDS (once) ----
    {
        int r = tid >> 4, kg = tid & 15;
        const float* fr = frow(feat, rowBase + r);
        #pragma unroll
        for (int q = 0; q < 4; ++q) {
            int k4 = (kg + 16 * q) * 4;
            *(float4*)&rowS[r][k4] = *(const float4*)(fr + k4);
        }
    }

    int labr[2], camr[2];
    float mi[2] = {NEGINF, NEGINF};   // id-neg running max
    float si[2] = {0.f, 0.f};         // id-neg running sum (rel. to mi)
    float mc[2] = {NEGINF, NEGINF};   // cam-neg running max
    float sc_[2] = {0.f, 0.f};        // cam-neg running sum (rel. to mc)
    #pragma unroll
    for (int i = 0; i < 2; ++i) {
        int gr = rowBase + ty * 2 + i;
        labr[i] = label[gr & (N_ - 1)];
        camr[i] = camid[gr & (N_ - 1)];
    }

    for (int t = 0; t < N2 / BN; ++t) {
        const int colBase = t * BN;
        float acc[2][4] = {{0.f,0.f,0.f,0.f},{0.f,0.f,0.f,0.f}};

        #pragma unroll 1
        for (int kc = 0; kc < D_ / KC; ++kc) {
            const int kBase = kc * KC;
            __syncthreads();   // previous chunk's compute done
            {
                int c = tid >> 2, kg = tid & 3;
                const float* fc = frow(feat, colBase + c);
                #pragma unroll
                for (int q = 0; q < 4; ++q) {
                    int kk4 = kg + 4 * q;   // float4 index within chunk
                    float4 v = *(const float4*)(fc + kBase + kk4 * 4);
                    colS[kk4 * 4 + 0][c] = v.x;
                    colS[kk4 * 4 + 1][c] = v.y;
                    colS[kk4 * 4 + 2][c] = v.z;
                    colS[kk4 * 4 + 3][c] = v.w;
                }
            }
            __syncthreads();

            const int r0 = ty * 2;
            #pragma unroll
            for (int kk = 0; kk < KC; kk += 4) {
                float4 a0 = *(const float4*)&rowS[r0 + 0][kBase + kk];
                float4 a1 = *(const float4*)&rowS[r0 + 1][kBase + kk];
                float4 b0 = *(const float4*)&colS[kk + 0][tx * 4];
                float4 b1 = *(const float4*)&colS[kk + 1][tx * 4];
                float4 b2 = *(const float4*)&colS[kk + 2][tx * 4];
                float4 b3 = *(const float4*)&colS[kk + 3][tx * 4];

                acc[0][0] += a0.x*b0.x; acc[0][1] += a0.x*b0.y; acc[0][2] += a0.x*b0.z; acc[0][3] += a0.x*b0.w;
                acc[1][0] += a1.x*b0.x; acc[1][1] += a1.x*b0.y; acc[1][2] += a1.x*b0.z; acc[1][3] += a1.x*b0.w;
                acc[0][0] += a0.y*b1.x; acc[0][1] += a0.y*b1.y; acc[0][2] += a0.y*b1.z; acc[0][3] += a0.y*b1.w;
                acc[1][0] += a1.y*b1.x; acc[1][1] += a1.y*b1.y; acc[1][2] += a1.y*b1.z; acc[1][3] += a1.y*b1.w;
                acc[0][0] += a0.z*b2.x; acc[0][1] += a0.z*b2.y; acc[0][2] += a0.z*b2.z; acc[0][3] += a0.z*b2.w;
                acc[1][0] += a1.z*b2.x; acc[1][1] += a1.z*b2.y; acc[1][2] += a1.z*b2.z; acc[1][3] += a1.z*b2.w;
                acc[0][0] += a0.w*b3.x; acc[0][1] += a0.w*b3.y; acc[0][2] += a0.w*b3.z; acc[0][3] += a0.w*b3.w;
                acc[1][0] += a1.w*b3.x; acc[1][1] += a1.w*b3.y; acc[1][2] += a1.w*b3.z; acc[1][3] += a1.w*b3.w;
            }
        }

        // column labels/cams for this thread's 4 columns (shared by both rows)
        int labc[4], camc[4];
        #pragma unroll
        for (int j = 0; j < 4; ++j) {
            int gc = colBase + tx * 4 + j;
            labc[j] = label[gc & (N_ - 1)];
            camc[j] = camid[gc & (N_ - 1)];
        }

        // online negative-set (max,sum) update, per branch
        #pragma unroll
        for (int i = 0; i < 2; ++i) {
            float lg[4];
            bool idn[4], cmn[4];
            #pragma unroll
            for (int j = 0; j < 4; ++j) {
                lg[j] = acc[i][j] * INV_TEMP;
                bool lm = (labc[j] == labr[i]);
                bool cm = lm && (camc[j] == camr[i]);
                idn[j] = !lm;   // id-branch negative
                cmn[j] = !cm;   // cam-branch negative
            }
            // ---- id branch ----
            {
                float t0 = idn[0] ? lg[0] : NEGINF;
                float t1 = idn[1] ? lg[1] : NEGINF;
                float t2 = idn[2] ? lg[2] : NEGINF;
                float t3 = idn[3] ? lg[3] : NEGINF;
                float tmax = fmaxf(fmaxf(t0, t1), fmaxf(t2, t3));
                float nm = fmaxf(mi[i], tmax);
                float sum = 0.f;
                #pragma unroll
                for (int j = 0; j < 4; ++j)
                    sum += idn[j] ? __expf(lg[j] - nm) : 0.f;  // select discards inf
                si[i] = si[i] * __expf(mi[i] - nm) + sum;
                mi[i] = nm;
            }
            // ---- cam branch ----
            {
                float t0 = cmn[0] ? lg[0] : NEGINF;
                float t1 = cmn[1] ? lg[1] : NEGINF;
                float t2 = cmn[2] ? lg[2] : NEGINF;
                float t3 = cmn[3] ? lg[3] : NEGINF;
                float tmax = fmaxf(fmaxf(t0, t1), fmaxf(t2, t3));
                float nm = fmaxf(mc[i], tmax);
                float sum = 0.f;
                #pragma unroll
                for (int j = 0; j < 4; ++j)
                    sum += cmn[j] ? __expf(lg[j] - nm) : 0.f;
                sc_[i] = sc_[i] * __expf(mc[i] - nm) + sum;
                mc[i] = nm;
            }
        }
    }

    // merge the 32 lanes (tx) that share each row; write c = m + log(s)
    #pragma unroll
    for (int i = 0; i < 2; ++i) {
        float m1 = mi[i], s1 = si[i];
        float m2 = mc[i], s2 = sc_[i];
        #pragma unroll
        for (int off = 16; off >= 1; off >>= 1) {
            float om1 = __shfl_xor(m1, off), os1 = __shfl_xor(s1, off);
            float om2 = __shfl_xor(m2, off), os2 = __shfl_xor(s2, off);
            float nm1 = fmaxf(m1, om1);
            s1 = s1 * __expf(m1 - nm1) + os1 * __expf(om1 - nm1);
            m1 = nm1;
            float nm2 = fmaxf(m2, om2);
            s2 = s2 * __expf(m2 - nm2) + os2 * __expf(om2 - nm2);
            m2 = nm2;
        }
        if (tx == 0) {
            int gr = rowBase + ty * 2 + i;
            stats[0 * N2 + gr] = m1 + __logf(s1);   // c_id
            stats[1 * N2 + gr] = m2 + __logf(s2);   // c_cam
        }
    }
}

// ---------------- Phase B: per-positive CE terms (one wave per row) ----------------
__global__ __launch_bounds__(256) void phaseB(const float* __restrict__ feat,
                                              const int* __restrict__ label,
                                              const int* __restrict__ camid,
                                              const float* __restrict__ stats,
                                              float* __restrict__ rowloss) {
    const int row  = blockIdx.x * 4 + (threadIdx.x >> 6);
    const int lane = threadIdx.x & 63;

    const float cid  = stats[0 * N2 + row];
    const float ccam = stats[1 * N2 + row];
    const int rl = label[row & (N_ - 1)];
    const int rc = camid[row & (N_ - 1)];

    const float* fi = frow(feat, row);
    float4 fi4 = *(const float4*)(fi + lane * 4);

    float sumid = 0.f, sumcam = 0.f, cntid = 0.f, cntcam = 0.f;

    for (int jj = 0; jj < N_; jj += 64) {
        int lj = label[jj + lane];
        int cj = camid[jj + lane];
        unsigned long long mk = __ballot(lj == rl);
        while (mk) {
            int b = __ffsll((unsigned long long)mk) - 1;
            mk &= mk - 1;
            int j0 = jj + b;
            bool cm = (__shfl(cj, b) == rc);
            #pragma unroll
            for (int h = 0; h < 2; ++h) {
                int c = j0 + h * N_;
                if (c == row) continue;          // wave-uniform
                const float* fc = frow(feat, c);
                float4 v = *(const float4*)(fc + lane * 4);
                float p = fi4.x*v.x + fi4.y*v.y + fi4.z*v.z + fi4.w*v.w;
                #pragma unroll
                for (int off = 32; off >= 1; off >>= 1) p += __shfl_xor(p, off);
                float a = p * INV_TEMP;          // lg_p
                // stable: LSE(a, c) - a
                {
                    float t = cid - a;
                    float term = (t <= 0.f) ? log1pf(__expf(t))
                                            : t + log1pf(__expf(-t));
                    sumid += term;
                    cntid += 1.f;
                }
                if (cm) {
                    float t = ccam - a;
                    float term = (t <= 0.f) ? log1pf(__expf(t))
                                            : t + log1pf(__expf(-t));
                    sumcam += term;
                    cntcam += 1.f;
                }
            }
        }
    }
    if (lane == 0)
        rowloss[row] = sumid / cntid + 0.5f * sumcam / cntcam;
}

// ---------------- Phase C: deterministic final reduce ----------------
__global__ __launch_bounds__(256) void phaseC(const float* __restrict__ rowloss,
                                              float* __restrict__ out) {
    __shared__ float red[256];
    float s = 0.f;
    for (int i = threadIdx.x; i < N2; i += 256) s += rowloss[i];
    red[threadIdx.x] = s;
    __syncthreads();
    for (int w = 128; w > 0; w >>= 1) {
        if (threadIdx.x < w) red[threadIdx.x] += red[threadIdx.x + w];
        __syncthreads();
    }
    if (threadIdx.x == 0) out[0] = red[0] / (float)N2;
}

extern "C" void kernel_launch(void* const* d_in, const int* in_sizes, int n_in,
                              void* d_out, int out_size, void* d_ws, size_t ws_size,
                              hipStream_t stream) {
    const float* feat  = (const float*)d_in[0];
    const int*   label = (const int*)d_in[1];
    const int*   camid = (const int*)d_in[2];
    float* stats   = (float*)d_ws;        // 2 * 8192 floats
    float* rowloss = stats + 2 * N2;      // 8192 floats

    phaseA<<<N2 / BM, 512, 0, stream>>>(feat, label, camid, stats);
    phaseB<<<N2 / 4, 256, 0, stream>>>(feat, label, camid, stats, rowloss);
    phaseC<<<1, 256, 0, stream>>>(rowloss, (float*)d_out);
}

// Round 3
// 214.965 us; speedup vs baseline: 3.6046x; 3.6046x over previous
//
#include <hip/hip_runtime.h>

typedef __attribute__((ext_vector_type(8))) short  s8v;   // 8 bf16 (4 VGPR)
typedef __attribute__((ext_vector_type(4))) float  f4v;   // MFMA accumulator

#define N_   4096
#define N2   8192
#define D_   256

constexpr float INV_TEMP = 10.0f;   // 1/0.1
constexpr float NEGINF   = -1e30f;

__device__ __forceinline__ const float* frow(const float* f, int r) {
    // logical row r of [2N, D]: features[N][2][D]
    return f + (size_t)(r & (N_ - 1)) * (2 * D_) + (size_t)((r >> 12) * D_);
}

__device__ __forceinline__ ushort f2bf(float x) {
    unsigned u = __float_as_uint(x);
    return (ushort)((u + 0x7FFFu + ((u >> 16) & 1u)) >> 16);   // RNE
}
__device__ __forceinline__ float bf2f(ushort b) {
    return __uint_as_float(((unsigned)b) << 16);
}

// ---------- convert: f32 [N,2,D] -> hi/lo bf16 [8192][256] (logical-row-major) ----------
__global__ __launch_bounds__(256) void convertK(const float* __restrict__ feat,
                                                ushort* __restrict__ fhi,
                                                ushort* __restrict__ flo) {
    int t = blockIdx.x * 256 + threadIdx.x;       // 262144 threads
    int r = t >> 5, g = t & 31;
    const float* src = frow(feat, r) + g * 8;
    float4 v0 = *(const float4*)src;
    float4 v1 = *(const float4*)(src + 4);
    float x[8] = {v0.x, v0.y, v0.z, v0.w, v1.x, v1.y, v1.z, v1.w};
    s8v h8, l8;
    #pragma unroll
    for (int i = 0; i < 8; ++i) {
        ushort h = f2bf(x[i]);
        h8[i] = (short)h;
        l8[i] = (short)f2bf(x[i] - bf2f(h));
    }
    *(s8v*)(fhi + (size_t)r * D_ + g * 8) = h8;
    *(s8v*)(flo + (size_t)r * D_ + g * 8) = l8;
}

// ---------- Phase A: 128x128 tile split-bf16 MFMA + per-tile id-neg (max,sum) ----------
// partial[ct][row] = (m, s) over id-negatives (label mismatch) in cols [ct*128, ct*128+128)
__global__ __launch_bounds__(256) void phaseA(const ushort* __restrict__ fhi,
                                              const ushort* __restrict__ flo,
                                              const int* __restrict__ label,
                                              float2* __restrict__ partial) {
    __shared__ ushort panels[4][128][64];   // Ahi | Alo | Bhi | Blo = 64 KB
    char* base = (char*)panels;

    const int tid  = threadIdx.x;
    const int lane = tid & 63;
    const int w    = tid >> 6;
    const int wr   = w >> 1, wc = w & 1;        // wave quadrant (rows, cols)
    const int ct = blockIdx.x & 63, rt = blockIdx.x >> 6;   // ct fastest: XCD gets 8 col-panels
    const int rowBase = rt * 128, colBase = ct * 128;

    f4v acc[4][4];
    #pragma unroll
    for (int i = 0; i < 4; ++i)
        #pragma unroll
        for (int j = 0; j < 4; ++j) acc[i][j] = (f4v){0.f, 0.f, 0.f, 0.f};

    const int skg = tid & 7;          // 16B k-group for staging
    const int sr0 = tid >> 3;         // rows 0..31 per q-step

    for (int kc = 0; kc < 4; ++kc) {
        const int kBase = kc * 64;
        __syncthreads();
        // stage: coalesced global (8 lanes cover one row's 128B), swizzled LDS write
        #pragma unroll
        for (int q = 0; q < 4; ++q) {
            int row = q * 32 + sr0;
            int off = row * 128 + ((skg * 16) ^ ((row & 7) << 4));
            size_t ga = (size_t)(rowBase + row) * D_ + kBase + skg * 8;
            size_t gb = (size_t)(colBase + row) * D_ + kBase + skg * 8;
            *(s8v*)(base + off)         = *(const s8v*)(fhi + ga);
            *(s8v*)(base + 16384 + off) = *(const s8v*)(flo + ga);
            *(s8v*)(base + 32768 + off) = *(const s8v*)(fhi + gb);
            *(s8v*)(base + 49152 + off) = *(const s8v*)(flo + gb);
        }
        __syncthreads();

        #pragma unroll
        for (int ks = 0; ks < 2; ++ks) {
            const int kb = ks * 64 + (lane >> 4) * 16;    // byte offset of lane's 8 bf16
            s8v ah[4], al[4], bh[4], bl[4];
            #pragma unroll
            for (int rf = 0; rf < 4; ++rf) {
                int row = wr * 64 + rf * 16 + (lane & 15);
                int off = row * 128 + (kb ^ ((row & 7) << 4));
                ah[rf] = *(const s8v*)(base + off);
                al[rf] = *(const s8v*)(base + 16384 + off);
            }
            #pragma unroll
            for (int cf = 0; cf < 4; ++cf) {
                int col = wc * 64 + cf * 16 + (lane & 15);
                int off = col * 128 + (kb ^ ((col & 7) << 4));
                bh[cf] = *(const s8v*)(base + 32768 + off);
                bl[cf] = *(const s8v*)(base + 49152 + off);
            }
            #pragma unroll
            for (int rf = 0; rf < 4; ++rf)
                #pragma unroll
                for (int cf = 0; cf < 4; ++cf) {
                    acc[rf][cf] = __builtin_amdgcn_mfma_f32_16x16x32_bf16(ah[rf], bh[cf], acc[rf][cf], 0, 0, 0);
                    acc[rf][cf] = __builtin_amdgcn_mfma_f32_16x16x32_bf16(al[rf], bh[cf], acc[rf][cf], 0, 0, 0);
                    acc[rf][cf] = __builtin_amdgcn_mfma_f32_16x16x32_bf16(ah[rf], bl[cf], acc[rf][cf], 0, 0, 0);
                }
        }
    }

    // ---- per-tile id-negative (max, sum) per row ----
    int rowlab[16], collab[4];
    #pragma unroll
    for (int rf = 0; rf < 4; ++rf)
        #pragma unroll
        for (int rg = 0; rg < 4; ++rg)
            rowlab[rf * 4 + rg] =
                label[(rowBase + wr * 64 + rf * 16 + (lane >> 4) * 4 + rg) & (N_ - 1)];
    #pragma unroll
    for (int cf = 0; cf < 4; ++cf)
        collab[cf] = label[(colBase + wc * 64 + cf * 16 + (lane & 15)) & (N_ - 1)];

    float mm[16], ss[16];
    #pragma unroll
    for (int rf = 0; rf < 4; ++rf)
        #pragma unroll
        for (int rg = 0; rg < 4; ++rg) {
            const int i = rf * 4 + rg;
            float lg[4];
            bool ng[4];
            #pragma unroll
            for (int cf = 0; cf < 4; ++cf) {
                lg[cf] = acc[rf][cf][rg] * INV_TEMP;
                ng[cf] = (collab[cf] != rowlab[i]);   // id-branch negative (diag auto-excluded)
            }
            float m = NEGINF;
            #pragma unroll
            for (int cf = 0; cf < 4; ++cf) m = ng[cf] ? fmaxf(m, lg[cf]) : m;
            float s = 0.f;
            #pragma unroll
            for (int cf = 0; cf < 4; ++cf) s += ng[cf] ? __expf(lg[cf] - m) : 0.f;
            mm[i] = m; ss[i] = s;
        }

    // butterfly over the 16 lanes (lane&15) sharing each row set
    #pragma unroll
    for (int off = 1; off < 16; off <<= 1) {
        #pragma unroll
        for (int i = 0; i < 16; ++i) {
            float om = __shfl_xor(mm[i], off), os = __shfl_xor(ss[i], off);
            float nm = fmaxf(mm[i], om);
            ss[i] = ss[i] * __expf(mm[i] - nm) + os * __expf(om - nm);
            mm[i] = nm;
        }
    }

    __syncthreads();                       // done with panels; reuse as merge buffer
    float2* mrg = (float2*)base;           // [128][2]
    if ((lane & 15) == 0) {
        #pragma unroll
        for (int rf = 0; rf < 4; ++rf)
            #pragma unroll
            for (int rg = 0; rg < 4; ++rg) {
                int rl = wr * 64 + rf * 16 + (lane >> 4) * 4 + rg;
                mrg[rl * 2 + wc] = make_float2(mm[rf * 4 + rg], ss[rf * 4 + rg]);
            }
    }
    __syncthreads();
    if (tid < 128) {
        float2 p0 = mrg[tid * 2 + 0], p1 = mrg[tid * 2 + 1];
        float nm = fmaxf(p0.x, p1.x);
        float s  = p0.y * __expf(p0.x - nm) + p1.y * __expf(p1.x - nm);
        partial[(size_t)ct * N2 + rowBase + tid] = make_float2(nm, s);
    }
}

// ---------- merge col-tile partials -> c_id[row] = log sum_{id-negs} exp(lg) ----------
__global__ __launch_bounds__(256) void mergeC(const float2* __restrict__ partial,
                                              float* __restrict__ cid) {
    int row = blockIdx.x * 256 + threadIdx.x;
    float m = NEGINF, s = 0.f;
    for (int ct = 0; ct < 64; ++ct) {          // fixed order: deterministic
        float2 p = partial[(size_t)ct * N2 + row];
        float nm = fmaxf(m, p.x);
        s = s * __expf(m - nm) + p.y * __expf(p.x - nm);
        m = nm;
    }
    cid[row] = m + __logf(s);
}

// ---------- Phase B: exact per-positive terms; builds c_cam from c_id + extras ----------
__global__ __launch_bounds__(256) void phaseB(const float* __restrict__ feat,
                                              const int* __restrict__ label,
                                              const int* __restrict__ camid,
                                              const float* __restrict__ cid_,
                                              float* __restrict__ rowloss) {
    const int row  = blockIdx.x * 4 + (threadIdx.x >> 6);
    const int lane = threadIdx.x & 63;
    const int rl = label[row & (N_ - 1)];
    const int rc = camid[row & (N_ - 1)];
    const float cid = cid_[row];
    const float* fi = frow(feat, row);
    float4 fi4 = *(const float4*)(fi + lane * 4);

    // pass 1: LSE over extras = {label-match && cam-mismatch} (exact fp32 dots)
    float mx = NEGINF, sx = 0.f;
    for (int jj = 0; jj < N_; jj += 64) {
        int lj = label[jj + lane], cj = camid[jj + lane];
        unsigned long long mk = __ballot(lj == rl);
        while (mk) {
            int b = __ffsll((unsigned long long)mk) - 1;
            mk &= mk - 1;
            bool cm = (__shfl(cj, b) == rc);
            if (!cm) {                       // row itself & its dup are cam-matches -> excluded
                #pragma unroll
                for (int h = 0; h < 2; ++h) {
                    int c = jj + b + h * N_;
                    const float* fc = frow(feat, c);
                    float4 v = *(const float4*)(fc + lane * 4);
                    float p = fi4.x * v.x + fi4.y * v.y + fi4.z * v.z + fi4.w * v.w;
                    #pragma unroll
                    for (int off = 32; off >= 1; off >>= 1) p += __shfl_xor(p, off);
                    float a = p * INV_TEMP;
                    float nm = fmaxf(mx, a);
                    sx = sx * __expf(mx - nm) + __expf(a - nm);
                    mx = nm;
                }
            }
        }
    }
    float ccam;
    if (sx > 0.f) {
        float xl = mx + __logf(sx);
        float d = xl - cid;
        ccam = (d <= 0.f) ? cid + log1pf(__expf(d)) : xl + log1pf(__expf(-d));
    } else {
        ccam = cid;
    }

    // pass 2: per-positive CE terms
    float sumid = 0.f, sumcam = 0.f, cntid = 0.f, cntcam = 0.f;
    for (int jj = 0; jj < N_; jj += 64) {
        int lj = label[jj + lane], cj = camid[jj + lane];
        unsigned long long mk = __ballot(lj == rl);
        while (mk) {
            int b = __ffsll((unsigned long long)mk) - 1;
            mk &= mk - 1;
            bool cm = (__shfl(cj, b) == rc);
            #pragma unroll
            for (int h = 0; h < 2; ++h) {
                int c = jj + b + h * N_;
                if (c == row) continue;      // wave-uniform
                const float* fc = frow(feat, c);
                float4 v = *(const float4*)(fc + lane * 4);
                float p = fi4.x * v.x + fi4.y * v.y + fi4.z * v.z + fi4.w * v.w;
                #pragma unroll
                for (int off = 32; off >= 1; off >>= 1) p += __shfl_xor(p, off);
                float a = p * INV_TEMP;
                {
                    float t = cid - a;
                    sumid += (t <= 0.f) ? log1pf(__expf(t)) : t + log1pf(__expf(-t));
                    cntid += 1.f;
                }
                if (cm) {
                    float t = ccam - a;
                    sumcam += (t <= 0.f) ? log1pf(__expf(t)) : t + log1pf(__expf(-t));
                    cntcam += 1.f;
                }
            }
        }
    }
    if (lane == 0)
        rowloss[row] = sumid / cntid + 0.5f * sumcam / cntcam;
}

// ---------- Phase C: deterministic final reduce ----------
__global__ __launch_bounds__(256) void phaseC(const float* __restrict__ rowloss,
                                              float* __restrict__ out) {
    __shared__ float red[256];
    float s = 0.f;
    for (int i = threadIdx.x; i < N2; i += 256) s += rowloss[i];
    red[threadIdx.x] = s;
    __syncthreads();
    for (int w = 128; w > 0; w >>= 1) {
        if (threadIdx.x < w) red[threadIdx.x] += red[threadIdx.x + w];
        __syncthreads();
    }
    if (threadIdx.x == 0) out[0] = red[0] / (float)N2;
}

extern "C" void kernel_launch(void* const* d_in, const int* in_sizes, int n_in,
                              void* d_out, int out_size, void* d_ws, size_t ws_size,
                              hipStream_t stream) {
    const float* feat  = (const float*)d_in[0];
    const int*   label = (const int*)d_in[1];
    const int*   camid = (const int*)d_in[2];

    ushort* fhi = (ushort*)d_ws;                                  // 4 MB
    ushort* flo = fhi + (size_t)N2 * D_;                          // 4 MB
    float2* partial = (float2*)((char*)d_ws + 8u * 1024 * 1024);  // 4 MB
    float*  cid     = (float*)((char*)d_ws + 12u * 1024 * 1024);  // 32 KB
    float*  rowloss = cid + N2;                                   // 32 KB

    convertK<<<1024, 256, 0, stream>>>(feat, fhi, flo);
    phaseA<<<4096, 256, 0, stream>>>(fhi, flo, label, partial);
    mergeC<<<32, 256, 0, stream>>>(partial, cid);
    phaseB<<<2048, 256, 0, stream>>>(feat, label, camid, cid, rowloss);
    phaseC<<<1, 256, 0, stream>>>(rowloss, (float*)d_out);
}

// Round 4
// 131.400 us; speedup vs baseline: 5.8970x; 1.6360x over previous
//
#include <hip/hip_runtime.h>

typedef __attribute__((ext_vector_type(8))) short  s8v;   // 8 bf16 (4 VGPR)
typedef __attribute__((ext_vector_type(4))) float  f4v;   // MFMA accumulator

#define N_   4096
#define N2   8192
#define D_   256

constexpr float INV_TEMP = 10.0f;   // 1/0.1
constexpr float NEGINF   = -1e30f;

__device__ __forceinline__ const float* frow(const float* f, int r) {
    // logical row r of [2N, D]: features[N][2][D]
    return f + (size_t)(r & (N_ - 1)) * (2 * D_) + (size_t)((r >> 12) * D_);
}

__device__ __forceinline__ ushort f2bf(float x) {
    unsigned u = __float_as_uint(x);
    return (ushort)((u + 0x7FFFu + ((u >> 16) & 1u)) >> 16);   // RNE
}
__device__ __forceinline__ float bf2f(ushort b) {
    return __uint_as_float(((unsigned)b) << 16);
}

// ---------- convert: f32 [N,2,D] -> hi/lo bf16 [8192][256] ----------
__global__ __launch_bounds__(256) void convertK(const float* __restrict__ feat,
                                                ushort* __restrict__ fhi,
                                                ushort* __restrict__ flo) {
    int t = blockIdx.x * 256 + threadIdx.x;
    int r = t >> 5, g = t & 31;
    const float* src = frow(feat, r) + g * 8;
    float4 v0 = *(const float4*)src;
    float4 v1 = *(const float4*)(src + 4);
    float x[8] = {v0.x, v0.y, v0.z, v0.w, v1.x, v1.y, v1.z, v1.w};
    s8v h8, l8;
    #pragma unroll
    for (int i = 0; i < 8; ++i) {
        ushort h = f2bf(x[i]);
        h8[i] = (short)h;
        l8[i] = (short)f2bf(x[i] - bf2f(h));
    }
    *(s8v*)(fhi + (size_t)r * D_ + g * 8) = h8;
    *(s8v*)(flo + (size_t)r * D_ + g * 8) = l8;
}

// ---------- Phase A: UPPER-TRIANGLE 128x128 tiles, row+col id-neg (max,sum) ----------
// partial[q][row]: (m, s) over id-negatives of global row `row` restricted to cols
// in panel q. Tile (rt,ct), rt<=ct: row-stats -> partial[ct][rt-rows];
// col-stats (rt<ct) -> partial[rt][ct-rows].  All 64*8192 slots written once.
__global__ __launch_bounds__(256) void phaseA(const ushort* __restrict__ fhi,
                                              const ushort* __restrict__ flo,
                                              const int* __restrict__ label,
                                              float2* __restrict__ partial) {
    __shared__ ushort panels[4][128][64];   // Ahi | Alo | Bhi | Blo = 64 KB
    char* base = (char*)panels;

    const int tid  = threadIdx.x;
    const int lane = tid & 63;
    const int w    = tid >> 6;
    const int wr   = w >> 1, wc = w & 1;

    // XCD swizzle (2080 = 8*260, bijective) then upper-tri decode
    int idx = (blockIdx.x & 7) * 260 + (blockIdx.x >> 3);
    int rt = 0, rem = idx;
    while (rem >= 64 - rt) { rem -= 64 - rt; ++rt; }
    const int ct = rt + rem;
    const bool offdiag = (ct != rt);
    const int rowBase = rt * 128, colBase = ct * 128;

    f4v acc[4][4];
    #pragma unroll
    for (int i = 0; i < 4; ++i)
        #pragma unroll
        for (int j = 0; j < 4; ++j) acc[i][j] = (f4v){0.f, 0.f, 0.f, 0.f};

    const int skg = tid & 7;
    const int sr0 = tid >> 3;

    for (int kc = 0; kc < 4; ++kc) {
        const int kBase = kc * 64;
        __syncthreads();
        #pragma unroll
        for (int q = 0; q < 4; ++q) {
            int row = q * 32 + sr0;
            int off = row * 128 + ((skg * 16) ^ ((row & 7) << 4));
            size_t ga = (size_t)(rowBase + row) * D_ + kBase + skg * 8;
            size_t gb = (size_t)(colBase + row) * D_ + kBase + skg * 8;
            *(s8v*)(base + off)         = *(const s8v*)(fhi + ga);
            *(s8v*)(base + 16384 + off) = *(const s8v*)(flo + ga);
            *(s8v*)(base + 32768 + off) = *(const s8v*)(fhi + gb);
            *(s8v*)(base + 49152 + off) = *(const s8v*)(flo + gb);
        }
        __syncthreads();

        #pragma unroll
        for (int ks = 0; ks < 2; ++ks) {
            const int kb = ks * 64 + (lane >> 4) * 16;
            s8v ah[4], al[4], bh[4], bl[4];
            #pragma unroll
            for (int rf = 0; rf < 4; ++rf) {
                int row = wr * 64 + rf * 16 + (lane & 15);
                int off = row * 128 + (kb ^ ((row & 7) << 4));
                ah[rf] = *(const s8v*)(base + off);
                al[rf] = *(const s8v*)(base + 16384 + off);
            }
            #pragma unroll
            for (int cf = 0; cf < 4; ++cf) {
                int col = wc * 64 + cf * 16 + (lane & 15);
                int off = col * 128 + (kb ^ ((col & 7) << 4));
                bh[cf] = *(const s8v*)(base + 32768 + off);
                bl[cf] = *(const s8v*)(base + 49152 + off);
            }
            #pragma unroll
            for (int rf = 0; rf < 4; ++rf)
                #pragma unroll
                for (int cf = 0; cf < 4; ++cf) {
                    acc[rf][cf] = __builtin_amdgcn_mfma_f32_16x16x32_bf16(ah[rf], bh[cf], acc[rf][cf], 0, 0, 0);
                    acc[rf][cf] = __builtin_amdgcn_mfma_f32_16x16x32_bf16(al[rf], bh[cf], acc[rf][cf], 0, 0, 0);
                    acc[rf][cf] = __builtin_amdgcn_mfma_f32_16x16x32_bf16(ah[rf], bl[cf], acc[rf][cf], 0, 0, 0);
                }
        }
    }

    // ================= epilogue =================
    __syncthreads();   // all panel reads done; LDS is reused below

    // LDS regions (floats): rowm[128][33], colm[128][9], mrowS[128], mcolS[128],
    //                       rows_s[128][33], cols_s[128][9]   (= 44 KB)
    float* fsm    = (float*)base;
    float* rowm   = fsm;
    float* colm   = fsm + 4224;
    float* mrowS  = fsm + 4224 + 1152;
    float* mcolS  = mrowS + 128;
    float* rows_s = mcolS + 128;
    float* cols_s = rows_s + 4224;

    const int grp32 = wc * 16 + (lane & 15);
    const int grp8  = wr * 4 + (lane >> 4);
    int rloc[16], cloc[4];
    int rowlab[16], collab[4];
    #pragma unroll
    for (int rf = 0; rf < 4; ++rf)
        #pragma unroll
        for (int rg = 0; rg < 4; ++rg) {
            int i = rf * 4 + rg;
            rloc[i] = wr * 64 + rf * 16 + (lane >> 4) * 4 + rg;
            rowlab[i] = label[(rowBase + rloc[i]) & (N_ - 1)];
        }
    #pragma unroll
    for (int cf = 0; cf < 4; ++cf) {
        cloc[cf] = wc * 64 + cf * 16 + (lane & 15);
        collab[cf] = label[(colBase + cloc[cf]) & (N_ - 1)];
    }

    // masked logits in place (positives & diagonal -> -1e30; exp later gives 0)
    #pragma unroll
    for (int rf = 0; rf < 4; ++rf)
        #pragma unroll
        for (int cf = 0; cf < 4; ++cf)
            #pragma unroll
            for (int rg = 0; rg < 4; ++rg) {
                float v = acc[rf][cf][rg] * INV_TEMP;
                acc[rf][cf][rg] = (collab[cf] == rowlab[rf * 4 + rg]) ? NEGINF : v;
            }

    // per-lane row maxes -> LDS
    #pragma unroll
    for (int rf = 0; rf < 4; ++rf)
        #pragma unroll
        for (int rg = 0; rg < 4; ++rg) {
            int i = rf * 4 + rg;
            float m = fmaxf(fmaxf(acc[rf][0][rg], acc[rf][1][rg]),
                            fmaxf(acc[rf][2][rg], acc[rf][3][rg]));
            rowm[rloc[i] * 33 + grp32] = m;
        }
    // per-lane col maxes -> LDS
    if (offdiag) {
        #pragma unroll
        for (int cf = 0; cf < 4; ++cf) {
            float m = NEGINF;
            #pragma unroll
            for (int rf = 0; rf < 4; ++rf)
                #pragma unroll
                for (int rg = 0; rg < 4; ++rg)
                    m = fmaxf(m, acc[rf][cf][rg]);
            colm[cloc[cf] * 9 + grp8] = m;
        }
    }
    __syncthreads();
    if (tid < 128) {
        float m = NEGINF;
        #pragma unroll
        for (int g = 0; g < 32; ++g) m = fmaxf(m, rowm[tid * 33 + g]);
        mrowS[tid] = m;
        if (offdiag) {
            float mc = NEGINF;
            #pragma unroll
            for (int g = 0; g < 8; ++g) mc = fmaxf(mc, colm[tid * 9 + g]);
            mcolS[tid] = mc;
        }
    }
    __syncthreads();

    float mr[16];
    #pragma unroll
    for (int i = 0; i < 16; ++i) mr[i] = mrowS[rloc[i]];
    float mcv[4];
    if (offdiag) {
        #pragma unroll
        for (int cf = 0; cf < 4; ++cf) mcv[cf] = mcolS[cloc[cf]];
    }

    float srl[16];
    #pragma unroll
    for (int i = 0; i < 16; ++i) srl[i] = 0.f;
    float scl[4] = {0.f, 0.f, 0.f, 0.f};
    #pragma unroll
    for (int rf = 0; rf < 4; ++rf)
        #pragma unroll
        for (int cf = 0; cf < 4; ++cf)
            #pragma unroll
            for (int rg = 0; rg < 4; ++rg) {
                int i = rf * 4 + rg;
                float v = acc[rf][cf][rg];
                srl[i] += __expf(v - mr[i]);
                if (offdiag) scl[cf] += __expf(v - mcv[cf]);
            }
    #pragma unroll
    for (int i = 0; i < 16; ++i) rows_s[rloc[i] * 33 + grp32] = srl[i];
    if (offdiag) {
        #pragma unroll
        for (int cf = 0; cf < 4; ++cf) cols_s[cloc[cf] * 9 + grp8] = scl[cf];
    }
    __syncthreads();
    if (tid < 128) {
        float s = 0.f;
        #pragma unroll
        for (int g = 0; g < 32; ++g) s += rows_s[tid * 33 + g];
        partial[(size_t)ct * N2 + rowBase + tid] = make_float2(mrowS[tid], s);
        if (offdiag) {
            float s2 = 0.f;
            #pragma unroll
            for (int g = 0; g < 8; ++g) s2 += cols_s[tid * 9 + g];
            partial[(size_t)rt * N2 + colBase + tid] = make_float2(mcolS[tid], s2);
        }
    }
}

// ---------- merge col-tile partials -> c_id[row] ----------
__global__ __launch_bounds__(256) void mergeC(const float2* __restrict__ partial,
                                              float* __restrict__ cid) {
    int row = blockIdx.x * 256 + threadIdx.x;
    float m = NEGINF, s = 0.f;
    for (int ct = 0; ct < 64; ++ct) {
        float2 p = partial[(size_t)ct * N2 + row];
        float nm = fmaxf(m, p.x);
        s = s * __expf(m - nm) + p.y * __expf(p.x - nm);
        m = nm;
    }
    cid[row] = m + __logf(s);
}

// ---------- Phase B: single-scan positive list, lane-parallel CE ----------
__global__ __launch_bounds__(256) void phaseB(const float* __restrict__ feat,
                                              const int* __restrict__ label,
                                              const int* __restrict__ camid,
                                              const float* __restrict__ cid_,
                                              float* __restrict__ rowloss) {
    __shared__ int   labS[N_], camS[N_];
    __shared__ float listA[4][128];
    __shared__ int   listF[4][128];

    const int tid = threadIdx.x, lane = tid & 63, w = tid >> 6;
    for (int i = tid; i < N_ / 4; i += 256) {
        *(int4*)&labS[i * 4] = *(const int4*)&label[i * 4];
        *(int4*)&camS[i * 4] = *(const int4*)&camid[i * 4];
    }
    __syncthreads();

    const int row = blockIdx.x * 4 + w;
    const int rl = labS[row & (N_ - 1)];
    const int rc = camS[row & (N_ - 1)];
    const float cid = cid_[row];
    const float* fi = frow(feat, row);
    float4 fi4 = *(const float4*)(fi + lane * 4);

    int cnt = 0;
    for (int jj = 0; jj < N_; jj += 64) {
        int lj = labS[jj + lane], cj = camS[jj + lane];
        unsigned long long mk = __ballot(lj == rl);
        while (mk) {
            int b = __ffsll((unsigned long long)mk) - 1;
            mk &= mk - 1;
            int cm = (__shfl(cj, b) == rc) ? 1 : 0;
            #pragma unroll
            for (int h = 0; h < 2; ++h) {
                int c = jj + b + h * N_;
                if (c == row) continue;          // wave-uniform
                const float* fc = frow(feat, c);
                float4 v = *(const float4*)(fc + lane * 4);
                float p = fi4.x * v.x + fi4.y * v.y + fi4.z * v.z + fi4.w * v.w;
                #pragma unroll
                for (int off = 32; off >= 1; off >>= 1) p += __shfl_xor(p, off);
                if (lane == 0) { listA[w][cnt] = p * INV_TEMP; listF[w][cnt] = cm; }
                ++cnt;                            // wave-uniform
            }
        }
    }

    // lane-parallel finish (cnt <= 64 in practice; list sized 128 for safety)
    float a_e = (lane < cnt) ? listA[w][lane] : NEGINF;
    int   f_e = (lane < cnt) ? listF[w][lane] : 1;

    // extras LSE (label-match, cam-mismatch)
    float xa = (f_e == 0) ? a_e : NEGINF;
    float mx = xa;
    #pragma unroll
    for (int off = 32; off >= 1; off >>= 1) mx = fmaxf(mx, __shfl_xor(mx, off));
    float xe = (f_e == 0) ? __expf(xa - mx) : 0.f;
    #pragma unroll
    for (int off = 32; off >= 1; off >>= 1) xe += __shfl_xor(xe, off);
    float ccam;
    if (xe > 0.f) {
        float xl = mx + __logf(xe);
        float d = xl - cid;
        ccam = (d <= 0.f) ? cid + log1pf(__expf(d)) : xl + log1pf(__expf(-d));
    } else {
        ccam = cid;
    }

    // per-positive terms
    float ti = cid - a_e;
    float termid = (ti <= 0.f) ? log1pf(__expf(ti)) : ti + log1pf(__expf(-ti));
    termid = (lane < cnt) ? termid : 0.f;
    float tc = ccam - a_e;
    float termcam = (tc <= 0.f) ? log1pf(__expf(tc)) : tc + log1pf(__expf(-tc));
    termcam = (lane < cnt && f_e) ? termcam : 0.f;
    #pragma unroll
    for (int off = 32; off >= 1; off >>= 1) {
        termid  += __shfl_xor(termid, off);
        termcam += __shfl_xor(termcam, off);
    }
    int ncam = __popcll(__ballot(lane < cnt && f_e));
    if (lane == 0)
        rowloss[row] = termid / (float)cnt + 0.5f * termcam / (float)ncam;
}

// ---------- Phase C: deterministic final reduce ----------
__global__ __launch_bounds__(256) void phaseC(const float* __restrict__ rowloss,
                                              float* __restrict__ out) {
    __shared__ float red[256];
    float s = 0.f;
    for (int i = threadIdx.x; i < N2; i += 256) s += rowloss[i];
    red[threadIdx.x] = s;
    __syncthreads();
    for (int w = 128; w > 0; w >>= 1) {
        if (threadIdx.x < w) red[threadIdx.x] += red[threadIdx.x + w];
        __syncthreads();
    }
    if (threadIdx.x == 0) out[0] = red[0] / (float)N2;
}

extern "C" void kernel_launch(void* const* d_in, const int* in_sizes, int n_in,
                              void* d_out, int out_size, void* d_ws, size_t ws_size,
                              hipStream_t stream) {
    const float* feat  = (const float*)d_in[0];
    const int*   label = (const int*)d_in[1];
    const int*   camid = (const int*)d_in[2];

    ushort* fhi = (ushort*)d_ws;                                  // 4 MB
    ushort* flo = fhi + (size_t)N2 * D_;                          // 4 MB
    float2* partial = (float2*)((char*)d_ws + 8u * 1024 * 1024);  // 4 MB
    float*  cid     = (float*)((char*)d_ws + 12u * 1024 * 1024);  // 32 KB
    float*  rowloss = cid + N2;                                   // 32 KB

    convertK<<<1024, 256, 0, stream>>>(feat, fhi, flo);
    phaseA<<<2080, 256, 0, stream>>>(fhi, flo, label, partial);
    mergeC<<<32, 256, 0, stream>>>(partial, cid);
    phaseB<<<2048, 256, 0, stream>>>(feat, label, camid, cid, rowloss);
    phaseC<<<1, 256, 0, stream>>>(rowloss, (float*)d_out);
}